// Round 1
// baseline (151.050 us; speedup 1.0000x reference)
//
#include <hip/hip_runtime.h>

typedef unsigned short ushort_t;
typedef __bf16 bf16_t;
typedef __attribute__((ext_vector_type(8))) bf16_t bf16x8;
typedef __attribute__((ext_vector_type(4))) float f32x4;

__device__ __forceinline__ ushort_t f2bf(float f) {
  unsigned int u = __builtin_bit_cast(unsigned int, f);
  u += 0x7FFFu + ((u >> 16) & 1u);
  return (ushort_t)(u >> 16);
}

__device__ __forceinline__ bf16x8 load8(const ushort_t* p) {
  union { ushort_t s[8]; bf16x8 v; } u;
#pragma unroll
  for (int j = 0; j < 8; ++j) u.s[j] = p[j];
  return u.v;
}

__device__ __forceinline__ f32x4 mfma16(bf16x8 a, bf16x8 b, f32x4 c) {
  return __builtin_amdgcn_mfma_f32_16x16x32_bf16(a, b, c, 0, 0, 0);
}

// Generic 64x64-tile MFMA GEMM: C[z] = A[z] @ B[z] + bias, A row-major [M,lda],
// B row-major [K,ldb], C row-major [M,ldc]. K % 32 == 0, tiles exact.
template <bool A_BF16, bool B_BF16, bool OUT_BF16>
__global__ __launch_bounds__(256) void gemm_k(
    const void* __restrict__ Ap, int lda, long long sA,
    const void* __restrict__ Bp, int ldb, long long sB,
    const float* __restrict__ bias,
    void* __restrict__ Cp, int ldc, long long sC,
    int M, int N, int K) {
  __shared__ ushort_t a_lds[64][34];
  __shared__ ushort_t b_lds[64][34];
  const int tid = threadIdx.x;
  const int n0 = blockIdx.x * 64;
  const int m0 = blockIdx.y * 64;
  const long long zo = blockIdx.z;
  const float*    Af = (const float*)Ap + zo * sA;
  const ushort_t* Ah = (const ushort_t*)Ap + zo * sA;
  const float*    Bf = (const float*)Bp + zo * sB;
  const ushort_t* Bh = (const ushort_t*)Bp + zo * sB;

  const int w = tid >> 6, l = tid & 63;
  const int l15 = l & 15, lhi = l >> 4;
  const int ma = tid >> 2, kga = (tid & 3) * 8;
  const int nb = tid & 63, kgb = (tid >> 6) * 8;

  f32x4 acc[4] = {};

  for (int k0 = 0; k0 < K; k0 += 32) {
    __syncthreads();
#pragma unroll
    for (int j = 0; j < 8; ++j) {
      int k = kga + j;
      size_t gi = (size_t)(m0 + ma) * lda + (k0 + k);
      a_lds[ma][k] = A_BF16 ? Ah[gi] : f2bf(Af[gi]);
    }
#pragma unroll
    for (int j = 0; j < 8; ++j) {
      int k = kgb + j;
      size_t gi = (size_t)(k0 + k) * ldb + (n0 + nb);
      b_lds[nb][k] = B_BF16 ? Bh[gi] : f2bf(Bf[gi]);
    }
    __syncthreads();
    bf16x8 af = load8(&a_lds[w * 16 + l15][lhi * 8]);
#pragma unroll
    for (int t = 0; t < 4; ++t) {
      bf16x8 bf = load8(&b_lds[t * 16 + l15][lhi * 8]);
      acc[t] = mfma16(af, bf, acc[t]);
    }
  }

#pragma unroll
  for (int t = 0; t < 4; ++t) {
#pragma unroll
    for (int r = 0; r < 4; ++r) {
      int row = m0 + w * 16 + lhi * 4 + r;
      int col = n0 + t * 16 + l15;
      float v = acc[t][r] + bias[col];
      size_t ci = (size_t)(zo * sC) + (size_t)row * ldc + col;
      if (OUT_BF16) ((ushort_t*)Cp)[ci] = f2bf(v);
      else          ((float*)Cp)[ci]    = v;
    }
  }
}

// S partial: per (b,h) and n-chunk of 256 rows, Sp[chunk][bh][64][64] = K_chunk^T @ V_chunk
__global__ __launch_bounds__(256) void kv_k(const ushort_t* __restrict__ qkv,
                                            float* __restrict__ Sp) {
  __shared__ ushort_t kt[64][34];
  __shared__ ushort_t vt[64][34];
  const int bh = blockIdx.x;         // 0..23
  const int chunk = blockIdx.y;      // 0..15
  const int b = bh / 12, h = bh % 12;
  const size_t base = (size_t)b * 4096 * 2304;
  const int koff = 768 + h * 64, voff = 1536 + h * 64;
  const int tid = threadIdx.x;
  const int d = tid & 63, ng = (tid >> 6) * 8;
  const int w = tid >> 6, l = tid & 63, l15 = l & 15, lhi = l >> 4;

  f32x4 acc[4] = {};
  const int nbeg = chunk * 256;
  for (int n0 = nbeg; n0 < nbeg + 256; n0 += 32) {
    __syncthreads();
#pragma unroll
    for (int j = 0; j < 8; ++j) {
      int nn = ng + j;
      size_t rowb = base + (size_t)(n0 + nn) * 2304;
      kt[d][nn] = qkv[rowb + koff + d];
      vt[d][nn] = qkv[rowb + voff + d];
    }
    __syncthreads();
    bf16x8 af = load8(&kt[w * 16 + l15][lhi * 8]);
#pragma unroll
    for (int t = 0; t < 4; ++t) {
      bf16x8 bf = load8(&vt[t * 16 + l15][lhi * 8]);
      acc[t] = mfma16(af, bf, acc[t]);
    }
  }
#pragma unroll
  for (int t = 0; t < 4; ++t) {
#pragma unroll
    for (int r = 0; r < 4; ++r) {
      int d1 = w * 16 + lhi * 4 + r;
      int d2 = t * 16 + l15;
      Sp[((size_t)chunk * 24 + bh) * 4096 + d1 * 64 + d2] = acc[t][r];
    }
  }
}

// reduce 16 chunks, fold 1/sqrt(64)
__global__ __launch_bounds__(256) void sred_k(const float* __restrict__ Sp,
                                              ushort_t* __restrict__ S) {
  int i = blockIdx.x * 256 + threadIdx.x;  // 0 .. 24*4096
  float a = 0.f;
#pragma unroll
  for (int c = 0; c < 16; ++c) a += Sp[(size_t)c * 98304 + i];
  S[i] = f2bf(a * 0.125f);
}

// T[b][h*64+d1][c] = sum_d2 S[bh][d1][d2] * w_proj[h*64+d2][c]
__global__ __launch_bounds__(256) void t_gemm_k(const ushort_t* __restrict__ S,
                                                const float* __restrict__ wproj,
                                                ushort_t* __restrict__ T) {
  __shared__ ushort_t a_lds[64][66];
  __shared__ ushort_t b_lds[64][66];
  const int n0 = blockIdx.x * 64;
  const int bh = blockIdx.y;
  const int b = bh / 12, h = bh % 12;
  const int tid = threadIdx.x;
  {
    int m = tid >> 2, kg = tid & 3;
#pragma unroll
    for (int j = 0; j < 16; ++j) {
      int k = kg * 16 + j;
      a_lds[m][k] = S[(size_t)bh * 4096 + m * 64 + k];
    }
    int n = tid & 63, kg2 = tid >> 6;
#pragma unroll
    for (int j = 0; j < 16; ++j) {
      int k = kg2 * 16 + j;
      b_lds[n][k] = f2bf(wproj[(size_t)(h * 64 + k) * 768 + n0 + n]);
    }
  }
  __syncthreads();
  const int w = tid >> 6, l = tid & 63, l15 = l & 15, lhi = l >> 4;
  f32x4 acc[4] = {};
#pragma unroll
  for (int kk = 0; kk < 64; kk += 32) {
    bf16x8 af = load8(&a_lds[w * 16 + l15][kk + lhi * 8]);
#pragma unroll
    for (int t = 0; t < 4; ++t) {
      bf16x8 bf = load8(&b_lds[t * 16 + l15][kk + lhi * 8]);
      acc[t] = mfma16(af, bf, acc[t]);
    }
  }
#pragma unroll
  for (int t = 0; t < 4; ++t) {
#pragma unroll
    for (int r = 0; r < 4; ++r) {
      int row = h * 64 + w * 16 + lhi * 4 + r;
      int col = n0 + t * 16 + l15;
      T[(size_t)b * 768 * 768 + (size_t)row * 768 + col] = f2bf(acc[t][r]);
    }
  }
}

extern "C" void kernel_launch(void* const* d_in, const int* in_sizes, int n_in,
                              void* d_out, int out_size, void* d_ws, size_t ws_size,
                              hipStream_t stream) {
  const float* x      = (const float*)d_in[0];
  const float* w_qkv  = (const float*)d_in[1];
  const float* b_qkv  = (const float*)d_in[2];
  const float* w_proj = (const float*)d_in[3];
  const float* b_proj = (const float*)d_in[4];
  float* out = (float*)d_out;

  char* ws = (char*)d_ws;
  ushort_t* qkv = (ushort_t*)ws;                  // 8192*2304 bf16 = 37,748,736 B
  ushort_t* S   = (ushort_t*)(ws + 37748736);     // 24*4096 bf16   =    196,608 B
  ushort_t* T   = (ushort_t*)(ws + 37945344);     // 2*768*768 bf16 =  2,359,296 B
  float*    Sp  = (float*)   (ws + 40304640);     // 16*24*4096 f32 =  6,291,456 B

  // 1) qkv = x @ w_qkv + b_qkv   -> bf16 [8192,2304]
  gemm_k<false, false, true><<<dim3(36, 128, 1), 256, 0, stream>>>(
      x, 768, 0LL, w_qkv, 2304, 0LL, b_qkv, qkv, 2304, 0LL, 8192, 2304, 768);
  // 2) per-(b,h) partial K^T V over 16 n-chunks
  kv_k<<<dim3(24, 16), 256, 0, stream>>>(qkv, Sp);
  // 3) reduce + 1/8
  sred_k<<<dim3(384), 256, 0, stream>>>(Sp, S);
  // 4) T[b] = blockstack_h(S_h @ Wproj_h)
  t_gemm_k<<<dim3(12, 24), 256, 0, stream>>>(S, w_proj, T);
  // 5) out[b] = Q[b] @ T[b] + b_proj  (fp32 out)
  gemm_k<true, true, false><<<dim3(12, 64, 2), 256, 0, stream>>>(
      qkv, 2304, 4096LL * 2304, T, 768, 768LL * 768, b_proj,
      out, 768, 4096LL * 768, 4096, 768, 768);
}

// Round 2
// 103.550 us; speedup vs baseline: 1.4587x; 1.4587x over previous
//
#include <hip/hip_runtime.h>

typedef unsigned short ushort_t;
typedef __bf16 bf16_t;
typedef __attribute__((ext_vector_type(8))) bf16_t bf16x8;
typedef __attribute__((ext_vector_type(4))) float f32x4;

__device__ __forceinline__ ushort_t f2bf(float f) {
  unsigned int u = __builtin_bit_cast(unsigned int, f);
  u += 0x7FFFu + ((u >> 16) & 1u);
  return (ushort_t)(u >> 16);
}

__device__ __forceinline__ f32x4 mfma16(bf16x8 a, bf16x8 b, f32x4 c) {
  return __builtin_amdgcn_mfma_f32_16x16x32_bf16(a, b, c, 0, 0, 0);
}

__device__ __forceinline__ void async_copy16(const void* g, void* l) {
  __builtin_amdgcn_global_load_lds(
      (const __attribute__((address_space(1))) unsigned int*)g,
      (__attribute__((address_space(3))) unsigned int*)l,
      16, 0, 0);
}

// ---------------- convert x (fp32) -> bf16, vectorized ----------------
__global__ __launch_bounds__(256) void conv_x_k(const float* __restrict__ x,
                                                ushort_t* __restrict__ xb) {
  int i = (blockIdx.x * 256 + threadIdx.x) * 8;
  float4 f0 = *(const float4*)(x + i);
  float4 f1 = *(const float4*)(x + i + 4);
  union { ushort_t s[8]; uint4 v; } u;
  u.s[0] = f2bf(f0.x); u.s[1] = f2bf(f0.y); u.s[2] = f2bf(f0.z); u.s[3] = f2bf(f0.w);
  u.s[4] = f2bf(f1.x); u.s[5] = f2bf(f1.y); u.s[6] = f2bf(f1.z); u.s[7] = f2bf(f1.w);
  *(uint4*)(xb + i) = u.v;
}

// ------- convert+transpose w_qkv [768][2304] fp32 -> wqt [2304][768] bf16 ----
__global__ __launch_bounds__(256) void conv_wt_k(const float* __restrict__ w,
                                                 ushort_t* __restrict__ wt) {
  __shared__ float lds[64][65];
  const int n0 = blockIdx.x * 64;   // column tile of w (row of wt)
  const int k0 = blockIdx.y * 64;   // row tile of w
  const int tid = threadIdx.x;
#pragma unroll
  for (int ii = 0; ii < 16; ++ii) {
    int lin = tid + ii * 256;
    int i = lin >> 6, j = lin & 63;
    lds[i][j] = w[(size_t)(k0 + i) * 2304 + n0 + j];
  }
  __syncthreads();
#pragma unroll
  for (int ii = 0; ii < 16; ++ii) {
    int lin = tid + ii * 256;
    int jj = lin >> 6, kk = lin & 63;
    wt[(size_t)(n0 + jj) * 768 + k0 + kk] = f2bf(lds[kk][jj]);
  }
}

// ---------------- fast 128x128-tile GEMM (m97 structure) ----------------
// C[z] = A[z] @ Bt[z]^T + bias.  A row-major [M,lda] bf16; Bt row-major [N,ldb]
// bf16 (i.e. B^T, k contiguous). K % 64 == 0, M % 128 == 0, N % 128 == 0.
template <bool OUT_BF16>
__global__ __launch_bounds__(256) void fgemm_k(
    const ushort_t* __restrict__ A, int lda, long long sA,
    const ushort_t* __restrict__ Bt, int ldb, long long sB,
    const float* __restrict__ bias,
    void* __restrict__ Cp, int ldc, long long sC,
    int K) {
  __shared__ char lds[32768];
  char* aL = lds;
  char* bL = lds + 16384;
  const int tid = threadIdx.x;
  const int n0 = blockIdx.x * 128;
  const int m0 = blockIdx.y * 128;
  const long long z = blockIdx.z;
  const ushort_t* Ab = A + z * sA + (size_t)m0 * lda;
  const ushort_t* Bb = Bt + z * sB + (size_t)n0 * ldb;

  const int w = tid >> 6, l = tid & 63;
  const int l15 = l & 15, lhi = l >> 4;
  const int rB = (w >> 1) * 64, cB = (w & 1) * 64;

  const int srow = tid >> 3;        // 0..31 (row within 32-row group)
  const int sseg = (tid & 7) << 4;  // byte seg 0..112

  f32x4 acc[4][4] = {};

  for (int k0 = 0; k0 < K; k0 += 64) {
#pragma unroll
    for (int i = 0; i < 4; ++i) {
      int row = i * 32 + srow;
      int sb = sseg ^ ((row & 7) << 4);  // inverse-swizzled source segment
      const char* ga = (const char*)(Ab + (size_t)row * lda + k0) + sb;
      const char* gb = (const char*)(Bb + (size_t)row * ldb + k0) + sb;
      async_copy16(ga, aL + i * 4096 + tid * 16);
      async_copy16(gb, bL + i * 4096 + tid * 16);
    }
    __syncthreads();
#pragma unroll
    for (int h = 0; h < 2; ++h) {
      bf16x8 af[4], bf[4];
#pragma unroll
      for (int m = 0; m < 4; ++m) {
        int row = rB + m * 16 + l15;
        int off = row * 128 + ((h * 64 + lhi * 16) ^ ((row & 7) << 4));
        af[m] = *(const bf16x8*)(aL + off);
      }
#pragma unroll
      for (int n = 0; n < 4; ++n) {
        int col = cB + n * 16 + l15;
        int off = col * 128 + ((h * 64 + lhi * 16) ^ ((col & 7) << 4));
        bf[n] = *(const bf16x8*)(bL + off);
      }
#pragma unroll
      for (int m = 0; m < 4; ++m)
#pragma unroll
        for (int n = 0; n < 4; ++n)
          acc[m][n] = mfma16(af[m], bf[n], acc[m][n]);
    }
    __syncthreads();
  }

#pragma unroll
  for (int m = 0; m < 4; ++m) {
#pragma unroll
    for (int n = 0; n < 4; ++n) {
#pragma unroll
      for (int r = 0; r < 4; ++r) {
        int row = m0 + rB + m * 16 + lhi * 4 + r;
        int col = n0 + cB + n * 16 + l15;
        float v = acc[m][n][r] + bias[col];
        size_t ci = (size_t)z * sC + (size_t)row * ldc + col;
        if (OUT_BF16) ((ushort_t*)Cp)[ci] = f2bf(v);
        else          ((float*)Cp)[ci]    = v;
      }
    }
  }
}

// S partial: per (b,h), n-chunk of 256: Sp[chunk][bh][64][64] = K_c^T @ V_c
__global__ __launch_bounds__(256) void kv_k(const ushort_t* __restrict__ qkv,
                                            float* __restrict__ Sp) {
  __shared__ ushort_t kt[64][34];
  __shared__ ushort_t vt[64][34];
  const int bh = blockIdx.x;
  const int chunk = blockIdx.y;
  const int b = bh / 12, h = bh % 12;
  const size_t base = (size_t)b * 4096 * 2304;
  const int koff = 768 + h * 64, voff = 1536 + h * 64;
  const int tid = threadIdx.x;
  const int d = tid & 63, ng = (tid >> 6) * 8;
  const int w = tid >> 6, l = tid & 63, l15 = l & 15, lhi = l >> 4;

  f32x4 acc[4] = {};
  const int nbeg = chunk * 256;
  for (int n0 = nbeg; n0 < nbeg + 256; n0 += 32) {
    __syncthreads();
#pragma unroll
    for (int j = 0; j < 8; ++j) {
      int nn = ng + j;
      size_t rowb = base + (size_t)(n0 + nn) * 2304;
      kt[d][nn] = qkv[rowb + koff + d];
      vt[d][nn] = qkv[rowb + voff + d];
    }
    __syncthreads();
    bf16x8 af = *(const bf16x8*)&kt[w * 16 + l15][lhi * 8];
#pragma unroll
    for (int t = 0; t < 4; ++t) {
      bf16x8 bf = *(const bf16x8*)&vt[t * 16 + l15][lhi * 8];
      acc[t] = mfma16(af, bf, acc[t]);
    }
  }
#pragma unroll
  for (int t = 0; t < 4; ++t) {
#pragma unroll
    for (int r = 0; r < 4; ++r) {
      int d1 = w * 16 + lhi * 4 + r;
      int d2 = t * 16 + l15;
      Sp[((size_t)chunk * 24 + bh) * 4096 + d1 * 64 + d2] = acc[t][r];
    }
  }
}

__global__ __launch_bounds__(256) void sred_k(const float* __restrict__ Sp,
                                              ushort_t* __restrict__ S) {
  int i = blockIdx.x * 256 + threadIdx.x;
  float a = 0.f;
#pragma unroll
  for (int c = 0; c < 16; ++c) a += Sp[(size_t)c * 98304 + i];
  S[i] = f2bf(a * 0.125f);
}

// Tt[b][c][h*64+d1] = sum_d2 S[bh][d1][d2] * w_proj[h*64+d2][c]   (transposed!)
__global__ __launch_bounds__(256) void t_gemm_k(const ushort_t* __restrict__ S,
                                                const float* __restrict__ wproj,
                                                ushort_t* __restrict__ Tt) {
  __shared__ ushort_t a_lds[64][66];
  __shared__ ushort_t b_lds[64][66];
  const int n0 = blockIdx.x * 64;
  const int bh = blockIdx.y;
  const int b = bh / 12, h = bh % 12;
  const int tid = threadIdx.x;
  {
    int m = tid >> 2, kg = tid & 3;
#pragma unroll
    for (int j = 0; j < 16; ++j) {
      int k = kg * 16 + j;
      a_lds[m][k] = S[(size_t)bh * 4096 + m * 64 + k];
    }
    int n = tid & 63, kg2 = tid >> 6;
#pragma unroll
    for (int j = 0; j < 16; ++j) {
      int k = kg2 * 16 + j;
      b_lds[n][k] = f2bf(wproj[(size_t)(h * 64 + k) * 768 + n0 + n]);
    }
  }
  __syncthreads();
  const int w = tid >> 6, l = tid & 63, l15 = l & 15, lhi = l >> 4;
  f32x4 acc[4] = {};
#pragma unroll
  for (int kk = 0; kk < 64; kk += 32) {
    bf16x8 af = *(const bf16x8*)&a_lds[w * 16 + l15][kk + lhi * 8];
#pragma unroll
    for (int t = 0; t < 4; ++t) {
      bf16x8 bf = *(const bf16x8*)&b_lds[t * 16 + l15][kk + lhi * 8];
      acc[t] = mfma16(af, bf, acc[t]);
    }
  }
#pragma unroll
  for (int t = 0; t < 4; ++t) {
#pragma unroll
    for (int r = 0; r < 4; ++r) {
      int row = h * 64 + w * 16 + lhi * 4 + r;
      int col = n0 + t * 16 + l15;
      Tt[(size_t)b * 768 * 768 + (size_t)col * 768 + row] = f2bf(acc[t][r]);
    }
  }
}

extern "C" void kernel_launch(void* const* d_in, const int* in_sizes, int n_in,
                              void* d_out, int out_size, void* d_ws, size_t ws_size,
                              hipStream_t stream) {
  const float* x      = (const float*)d_in[0];
  const float* w_qkv  = (const float*)d_in[1];
  const float* b_qkv  = (const float*)d_in[2];
  const float* w_proj = (const float*)d_in[3];
  const float* b_proj = (const float*)d_in[4];
  float* out = (float*)d_out;

  char* ws = (char*)d_ws;
  ushort_t* qkv = (ushort_t*)ws;                     // 37,748,736 B
  ushort_t* xb  = (ushort_t*)(ws + 37748736);        // 12,582,912 B (dead after qkv GEMM)
  ushort_t* wqt = (ushort_t*)(ws + 50331648);        //  3,538,944 B (dead after qkv GEMM)
  float*    Sp  = (float*)   (ws + 37748736);        //  6,291,456 B (aliases xb)
  ushort_t* S   = (ushort_t*)(ws + 50331648);        //    196,608 B (aliases wqt)
  ushort_t* Tt  = (ushort_t*)(ws + 50528256);        //  2,359,296 B

  // 0a) x -> bf16
  conv_x_k<<<dim3(3072), 256, 0, stream>>>(x, xb);
  // 0b) w_qkv -> bf16 transposed [2304][768]
  conv_wt_k<<<dim3(36, 12), 256, 0, stream>>>(w_qkv, wqt);
  // 1) qkv = x @ w_qkv + b_qkv -> bf16 [8192][2304]
  fgemm_k<true><<<dim3(18, 64, 1), 256, 0, stream>>>(
      xb, 768, 0LL, wqt, 768, 0LL, b_qkv, qkv, 2304, 0LL, 768);
  // 2) per-(b,h) partial K^T V over 16 n-chunks
  kv_k<<<dim3(24, 16), 256, 0, stream>>>(qkv, Sp);
  // 3) reduce + 1/8
  sred_k<<<dim3(384), 256, 0, stream>>>(Sp, S);
  // 4) Tt[b] = (blockstack_h(S_h @ Wproj_h))^T
  t_gemm_k<<<dim3(12, 24), 256, 0, stream>>>(S, w_proj, Tt);
  // 5) out[b] = Q[b] @ Tt[b]^T + b_proj (fp32 out)
  fgemm_k<false><<<dim3(6, 32, 2), 256, 0, stream>>>(
      qkv, 2304, 4096LL * 2304, Tt, 768, 768LL * 768, b_proj,
      out, 768, 4096LL * 768, 768);
}

// Round 3
// 101.776 us; speedup vs baseline: 1.4841x; 1.0174x over previous
//
#include <hip/hip_runtime.h>

typedef unsigned short ushort_t;
typedef __bf16 bf16_t;
typedef __attribute__((ext_vector_type(8))) bf16_t bf16x8;
typedef __attribute__((ext_vector_type(4))) float f32x4;

__device__ __forceinline__ ushort_t f2bf(float f) {
  unsigned int u = __builtin_bit_cast(unsigned int, f);
  u += 0x7FFFu + ((u >> 16) & 1u);
  return (ushort_t)(u >> 16);
}

__device__ __forceinline__ f32x4 mfma16(bf16x8 a, bf16x8 b, f32x4 c) {
  return __builtin_amdgcn_mfma_f32_16x16x32_bf16(a, b, c, 0, 0, 0);
}

__device__ __forceinline__ void async_copy16(const void* g, void* l) {
  __builtin_amdgcn_global_load_lds(
      (const __attribute__((address_space(1))) unsigned int*)g,
      (__attribute__((address_space(3))) unsigned int*)l,
      16, 0, 0);
}

// ---------------- convert x (fp32) -> bf16, vectorized ----------------
__global__ __launch_bounds__(256) void conv_x_k(const float* __restrict__ x,
                                                ushort_t* __restrict__ xb) {
  int i = (blockIdx.x * 256 + threadIdx.x) * 8;
  float4 f0 = *(const float4*)(x + i);
  float4 f1 = *(const float4*)(x + i + 4);
  union { ushort_t s[8]; uint4 v; } u;
  u.s[0] = f2bf(f0.x); u.s[1] = f2bf(f0.y); u.s[2] = f2bf(f0.z); u.s[3] = f2bf(f0.w);
  u.s[4] = f2bf(f1.x); u.s[5] = f2bf(f1.y); u.s[6] = f2bf(f1.z); u.s[7] = f2bf(f1.w);
  *(uint4*)(xb + i) = u.v;
}

// ------- convert+transpose w_qkv [768][2304] fp32 -> wqt [2304][768] bf16 ----
__global__ __launch_bounds__(256) void conv_wt_k(const float* __restrict__ w,
                                                 ushort_t* __restrict__ wt) {
  __shared__ float lds[64][65];
  const int n0 = blockIdx.x * 64;
  const int k0 = blockIdx.y * 64;
  const int tid = threadIdx.x;
#pragma unroll
  for (int ii = 0; ii < 16; ++ii) {
    int lin = tid + ii * 256;
    int i = lin >> 6, j = lin & 63;
    lds[i][j] = w[(size_t)(k0 + i) * 2304 + n0 + j];
  }
  __syncthreads();
#pragma unroll
  for (int ii = 0; ii < 16; ++ii) {
    int lin = tid + ii * 256;
    int jj = lin >> 6, kk = lin & 63;
    wt[(size_t)(n0 + jj) * 768 + k0 + kk] = f2bf(lds[kk][jj]);
  }
}

// =============== 256x256 8-phase GEMM (m201-style template) ===============
// C[z] = A[z] @ Bt[z]^T + bias. A:[M][lda] bf16, Bt:[N][ldb] bf16 (k-contig).
// K % 128 == 0, M % 256 == 0, N % 256 == 0, gridDim.x % 8 == 0.
template <bool OUT_BF16>
__global__ __launch_bounds__(512, 2) void gemm8p_k(
    const ushort_t* __restrict__ A, int lda, long long sA,
    const ushort_t* __restrict__ Bt, int ldb, long long sB,
    const float* __restrict__ bias,
    void* __restrict__ Cp, int ldc, long long sC,
    int K, int ntiles) {
  __shared__ char smem[131072];  // 2 buf x (A 32K + B 32K), halves of 16K
  const int tid = threadIdx.x;
  const int lane = tid & 63;
  const int wid = tid >> 6;             // 0..7
  const int l15 = lane & 15, lhi = lane >> 4;
  const int wr = wid >> 2, wc = wid & 3;  // 2M x 4N wave grid
  const int sx = l15 & 7;

  // XCD-aware swizzle (nwg % 8 == 0 in all launches)
  const int nwg = gridDim.x;
  const int q = nwg >> 3;
  const int swz = (blockIdx.x & 7) * q + (blockIdx.x >> 3);
  const int mt = swz / ntiles, nt = swz % ntiles;
  const int m0 = mt << 8, n0 = nt << 8;
  const long long z = blockIdx.y;

  const ushort_t* Ab = A + z * sA;
  const ushort_t* Bb = Bt + z * sB;

  // staging geometry: thread handles chunks (r0,sg) and (r0+64,sg) of a half
  const int r0 = tid >> 3;            // 0..63
  const int sg = tid & 7;
  const int soff = (sg ^ (r0 & 7)) << 4;  // (r0+64)&7 == r0&7

#define STAGE_A(BUF, H, K0)                                                      \
  { const char* g0 = (const char*)(Ab + (size_t)(m0 + (H)*128 + r0) * lda + (K0)) + soff;      \
    const char* g1 = (const char*)(Ab + (size_t)(m0 + (H)*128 + r0 + 64) * lda + (K0)) + soff; \
    char* lb = smem + (BUF)*65536 + (H)*16384;                                   \
    async_copy16(g0, lb + tid * 16);                                             \
    async_copy16(g1, lb + 8192 + tid * 16); }

#define STAGE_B(BUF, H, K0)                                                      \
  { const char* g0 = (const char*)(Bb + (size_t)(n0 + (H)*128 + r0) * ldb + (K0)) + soff;      \
    const char* g1 = (const char*)(Bb + (size_t)(n0 + (H)*128 + r0 + 64) * ldb + (K0)) + soff; \
    char* lb = smem + (BUF)*65536 + 32768 + (H)*16384;                           \
    async_copy16(g0, lb + tid * 16);                                             \
    async_copy16(g1, lb + 8192 + tid * 16); }

  // ds-read geometry
  const int aBase = wr * 16384 + l15 * 128;
  const int bBase = 32768 + (wc >> 1) * 16384 + ((wc & 1) * 64 + l15) * 128;
  const int sk0 = ((lhi ^ sx) << 4);
  const int sk1 = (((4 + lhi) ^ sx) << 4);

  f32x4 acc[8][4] = {};
  bf16x8 bfr[4][2];

#define DS_A(BUF, MPAIR, AF)                                                     \
  _Pragma("unroll") for (int mm = 0; mm < 2; ++mm) {                             \
    AF[mm][0] = *(const bf16x8*)(smem + (BUF)*65536 + aBase + ((MPAIR)*2+mm)*2048 + sk0); \
    AF[mm][1] = *(const bf16x8*)(smem + (BUF)*65536 + aBase + ((MPAIR)*2+mm)*2048 + sk1); }

#define DS_B(BUF)                                                                \
  _Pragma("unroll") for (int n = 0; n < 4; ++n) {                                \
    bfr[n][0] = *(const bf16x8*)(smem + (BUF)*65536 + bBase + n*2048 + sk0);     \
    bfr[n][1] = *(const bf16x8*)(smem + (BUF)*65536 + bBase + n*2048 + sk1); }

#define MFMA_PH(MPAIR, AF)                                                       \
  __builtin_amdgcn_s_setprio(1);                                                 \
  _Pragma("unroll") for (int mm = 0; mm < 2; ++mm)                               \
    _Pragma("unroll") for (int n = 0; n < 4; ++n) {                              \
      acc[(MPAIR)*2+mm][n] = mfma16(AF[mm][0], bfr[n][0], acc[(MPAIR)*2+mm][n]); \
      acc[(MPAIR)*2+mm][n] = mfma16(AF[mm][1], bfr[n][1], acc[(MPAIR)*2+mm][n]); } \
  __builtin_amdgcn_s_setprio(0);

#define BARRIER { __builtin_amdgcn_s_barrier(); asm volatile("" ::: "memory"); }
#define VMW4 asm volatile("s_waitcnt vmcnt(4)" ::: "memory")

  // prologue: tile0 (A+B) -> buf0, tile1 B -> buf1
  STAGE_A(0, 0, 0) STAGE_A(0, 1, 0)
  STAGE_B(0, 0, 0) STAGE_B(0, 1, 0)
  STAGE_B(1, 0, 64) STAGE_B(1, 1, 64)
  VMW4;
  BARRIER

  const int NIT = K >> 7;  // 2 K-tiles (2x64) per iteration
#pragma unroll 1
  for (int it = 0; it < NIT; ++it) {
    const int kA = (it << 7) + 64;                      // tile 2it+1 (always < K)
    int k2 = (it << 7) + 128; if (k2 >= K) k2 -= K;     // tile 2it+2 (wrap-safe)
    int k3 = (it << 7) + 192; if (k3 >= K) k3 -= K;     // tile 2it+3 (wrap-safe)
    { bf16x8 af[2][2]; DS_B(0) DS_A(0, 0, af) STAGE_A(1, 0, kA)
      BARRIER MFMA_PH(0, af) BARRIER }
    { bf16x8 af[2][2]; DS_A(0, 1, af) STAGE_A(1, 1, kA)
      BARRIER MFMA_PH(1, af) BARRIER }
    { bf16x8 af[2][2]; DS_A(0, 2, af) STAGE_B(0, 0, k2)
      BARRIER MFMA_PH(2, af) BARRIER }
    { bf16x8 af[2][2]; DS_A(0, 3, af) STAGE_B(0, 1, k2) VMW4;
      BARRIER MFMA_PH(3, af) BARRIER }
    { bf16x8 af[2][2]; DS_B(1) DS_A(1, 0, af) STAGE_A(0, 0, k2)
      BARRIER MFMA_PH(0, af) BARRIER }
    { bf16x8 af[2][2]; DS_A(1, 1, af) STAGE_A(0, 1, k2)
      BARRIER MFMA_PH(1, af) BARRIER }
    { bf16x8 af[2][2]; DS_A(1, 2, af) STAGE_B(1, 0, k3)
      BARRIER MFMA_PH(2, af) BARRIER }
    { bf16x8 af[2][2]; DS_A(1, 3, af) STAGE_B(1, 1, k3) VMW4;
      BARRIER MFMA_PH(3, af) BARRIER }
  }
  asm volatile("s_waitcnt vmcnt(0)" ::: "memory");

  float bv[4];
#pragma unroll
  for (int n = 0; n < 4; ++n) bv[n] = bias[n0 + wc * 64 + n * 16 + l15];
#pragma unroll
  for (int m = 0; m < 8; ++m) {
#pragma unroll
    for (int n = 0; n < 4; ++n) {
#pragma unroll
      for (int ri = 0; ri < 4; ++ri) {
        int row = m0 + wr * 128 + m * 16 + lhi * 4 + ri;
        int col = n0 + wc * 64 + n * 16 + l15;
        float v = acc[m][n][ri] + bv[n];
        size_t ci = (size_t)z * sC + (size_t)row * ldc + col;
        if (OUT_BF16) ((ushort_t*)Cp)[ci] = f2bf(v);
        else          ((float*)Cp)[ci]    = v;
      }
    }
  }
}

// S partial: per (b,h), n-chunk of 256: Sp[chunk][bh][64][64] = K_c^T @ V_c
__global__ __launch_bounds__(256) void kv_k(const ushort_t* __restrict__ qkv,
                                            float* __restrict__ Sp) {
  __shared__ ushort_t kt[64][34];
  __shared__ ushort_t vt[64][34];
  const int bh = blockIdx.x;
  const int chunk = blockIdx.y;
  const int b = bh / 12, h = bh % 12;
  const size_t base = (size_t)b * 4096 * 2304;
  const int koff = 768 + h * 64, voff = 1536 + h * 64;
  const int tid = threadIdx.x;
  const int d = tid & 63, ng = (tid >> 6) * 8;
  const int w = tid >> 6, l = tid & 63, l15 = l & 15, lhi = l >> 4;

  f32x4 acc[4] = {};
  const int nbeg = chunk * 256;
  for (int n0 = nbeg; n0 < nbeg + 256; n0 += 32) {
    __syncthreads();
#pragma unroll
    for (int j = 0; j < 8; ++j) {
      int nn = ng + j;
      size_t rowb = base + (size_t)(n0 + nn) * 2304;
      kt[d][nn] = qkv[rowb + koff + d];
      vt[d][nn] = qkv[rowb + voff + d];
    }
    __syncthreads();
    bf16x8 af = *(const bf16x8*)&kt[w * 16 + l15][lhi * 8];
#pragma unroll
    for (int t = 0; t < 4; ++t) {
      bf16x8 bf = *(const bf16x8*)&vt[t * 16 + l15][lhi * 8];
      acc[t] = mfma16(af, bf, acc[t]);
    }
  }
#pragma unroll
  for (int t = 0; t < 4; ++t) {
#pragma unroll
    for (int r = 0; r < 4; ++r) {
      int d1 = w * 16 + lhi * 4 + r;
      int d2 = t * 16 + l15;
      Sp[((size_t)chunk * 24 + bh) * 4096 + d1 * 64 + d2] = acc[t][r];
    }
  }
}

__global__ __launch_bounds__(256) void sred_k(const float* __restrict__ Sp,
                                              ushort_t* __restrict__ S) {
  int i = blockIdx.x * 256 + threadIdx.x;
  float a = 0.f;
#pragma unroll
  for (int c = 0; c < 16; ++c) a += Sp[(size_t)c * 98304 + i];
  S[i] = f2bf(a * 0.125f);
}

// Tt[b][c][h*64+d1] = sum_d2 S[bh][d1][d2] * w_proj[h*64+d2][c]   (transposed)
__global__ __launch_bounds__(256) void t_gemm_k(const ushort_t* __restrict__ S,
                                                const float* __restrict__ wproj,
                                                ushort_t* __restrict__ Tt) {
  __shared__ ushort_t a_lds[64][66];
  __shared__ ushort_t b_lds[64][66];
  const int n0 = blockIdx.x * 64;
  const int bh = blockIdx.y;
  const int b = bh / 12, h = bh % 12;
  const int tid = threadIdx.x;
  {
    int m = tid >> 2, kg = tid & 3;
#pragma unroll
    for (int j = 0; j < 16; ++j) {
      int k = kg * 16 + j;
      a_lds[m][k] = S[(size_t)bh * 4096 + m * 64 + k];
    }
    int n = tid & 63, kg2 = tid >> 6;
#pragma unroll
    for (int j = 0; j < 16; ++j) {
      int k = kg2 * 16 + j;
      b_lds[n][k] = f2bf(wproj[(size_t)(h * 64 + k) * 768 + n0 + n]);
    }
  }
  __syncthreads();
  const int w = tid >> 6, l = tid & 63, l15 = l & 15, lhi = l >> 4;
  f32x4 acc[4] = {};
#pragma unroll
  for (int kk = 0; kk < 64; kk += 32) {
    bf16x8 af = *(const bf16x8*)&a_lds[w * 16 + l15][kk + lhi * 8];
#pragma unroll
    for (int t = 0; t < 4; ++t) {
      bf16x8 bf = *(const bf16x8*)&b_lds[t * 16 + l15][kk + lhi * 8];
      acc[t] = mfma16(af, bf, acc[t]);
    }
  }
#pragma unroll
  for (int t = 0; t < 4; ++t) {
#pragma unroll
    for (int r = 0; r < 4; ++r) {
      int row = h * 64 + w * 16 + lhi * 4 + r;
      int col = n0 + t * 16 + l15;
      Tt[(size_t)b * 768 * 768 + (size_t)col * 768 + row] = f2bf(acc[t][r]);
    }
  }
}

extern "C" void kernel_launch(void* const* d_in, const int* in_sizes, int n_in,
                              void* d_out, int out_size, void* d_ws, size_t ws_size,
                              hipStream_t stream) {
  const float* x      = (const float*)d_in[0];
  const float* w_qkv  = (const float*)d_in[1];
  const float* b_qkv  = (const float*)d_in[2];
  const float* w_proj = (const float*)d_in[3];
  const float* b_proj = (const float*)d_in[4];
  float* out = (float*)d_out;

  char* ws = (char*)d_ws;
  ushort_t* qkv = (ushort_t*)ws;                     // 37,748,736 B
  ushort_t* xb  = (ushort_t*)(ws + 37748736);        // 12,582,912 B (dead after qkv GEMM)
  ushort_t* wqt = (ushort_t*)(ws + 50331648);        //  3,538,944 B (dead after qkv GEMM)
  float*    Sp  = (float*)   (ws + 37748736);        //  6,291,456 B (aliases xb)
  ushort_t* S   = (ushort_t*)(ws + 50331648);        //    196,608 B (aliases wqt)
  ushort_t* Tt  = (ushort_t*)(ws + 50528256);        //  2,359,296 B

  // 0a) x -> bf16
  conv_x_k<<<dim3(3072), 256, 0, stream>>>(x, xb);
  // 0b) w_qkv -> bf16 transposed [2304][768]
  conv_wt_k<<<dim3(36, 12), 256, 0, stream>>>(w_qkv, wqt);
  // 1) qkv = x @ w_qkv + b_qkv -> bf16 [8192][2304]  (32 mtiles x 9 ntiles)
  gemm8p_k<true><<<dim3(288, 1), 512, 0, stream>>>(
      xb, 768, 0LL, wqt, 768, 0LL, b_qkv, qkv, 2304, 0LL, 768, 9);
  // 2) per-(b,h) partial K^T V over 16 n-chunks
  kv_k<<<dim3(24, 16), 256, 0, stream>>>(qkv, Sp);
  // 3) reduce + 1/8
  sred_k<<<dim3(384), 256, 0, stream>>>(Sp, S);
  // 4) Tt[b] = (blockstack_h(S_h @ Wproj_h))^T
  t_gemm_k<<<dim3(12, 24), 256, 0, stream>>>(S, w_proj, Tt);
  // 5) out[b] = Q[b] @ Tt[b]^T + b_proj (fp32 out)   (16 mtiles x 3 ntiles, z=2)
  gemm8p_k<false><<<dim3(48, 2), 512, 0, stream>>>(
      qkv, 2304, 4096LL * 2304, Tt, 768, 768LL * 768, b_proj,
      out, 768, 4096LL * 768, 768, 3);
}